// Round 11
// baseline (146.747 us; speedup 1.0000x reference)
//
#include <hip/hip_runtime.h>
#include <hip/hip_bf16.h>
#include <stdint.h>

// B=16, K=8, N=196, D=768, H=3072, DOUT=768
// y[b,n,:] = (mean_k relu(slots[b,k]@W1 + pos[n]@W1 + b1)) @ W2 + b2
// (softmax over K of K-identical values is exactly 1/K; map_alpha unused)
//
// Dispatches:
//  k_prep:      W1->W1t atoms + A1=[slots;pos] atoms (bf16)
//  k_gemm1_w2t: C1 = A1 @ W1t^T (288 tiles, XCD nt-swizzle) + W2->W2t (1152 blks)
//  k_hbar:      Hb atoms (50 row-atoms, clamped)
//  k_gemm2:     out = Hb @ W2t^T + b2. BM=128,BN=64, 2 waves x wave-tile 64x64
//               (min LDS-read redundancy: A x1, B x2), 3-stage, rt-XCD swizzle.
// Atom = 64x64 bf16 tile, image [kb 0..7][r 0..63] chunks of 8; off=(kb*64+r)*8.

typedef __attribute__((ext_vector_type(8))) short bf16x8;
typedef __attribute__((ext_vector_type(4))) float f32x4;

#define AS1 __attribute__((address_space(1)))
#define AS3 __attribute__((address_space(3)))

#define WAIT_VM(N) asm volatile("s_waitcnt vmcnt(" #N ")" ::: "memory")
#define BAR()      asm volatile("s_barrier" ::: "memory")
#define BAR_LDS()  asm volatile("s_waitcnt lgkmcnt(0)\ns_barrier" ::: "memory")

static __device__ __forceinline__ void gld_lds16(const void* g, void* l) {
    __builtin_amdgcn_global_load_lds((const AS1 unsigned int*)g,
                                     (AS3 unsigned int*)l, 16, 0, 0);
}

static __device__ __forceinline__ unsigned short f2bf(float f) {
    union { float f; unsigned int u; } v; v.f = f;
    unsigned int u = v.u;
    return (unsigned short)((u + 0x7fffu + ((u >> 16) & 1u)) >> 16);  // RNE
}

// ---------------- prep: W1t tiled transpose + A1 tiled pack ----------------
__global__ void k_prep(const float* __restrict__ W1, unsigned short* __restrict__ W1t,
                       const float* __restrict__ S, const float* __restrict__ P,
                       unsigned short* __restrict__ A1) {
    int idx = blockIdx.x * blockDim.x + threadIdx.x;
    const int C1n = 96 * 3072;          // W1t tasks
    const int PKn = 96 * 384;           // A1 tasks
    if (idx < C1n) {
        int r  = idx % 3072;            // consecutive tid -> consecutive r (coalesced)
        int kc = idx / 3072;            // 8-elem k-chunk (0..95)
        unsigned int po[4];
        #pragma unroll
        for (int j = 0; j < 4; ++j) {
            unsigned short lo = f2bf(W1[(size_t)(kc * 8 + 2 * j) * 3072 + r]);
            unsigned short hi = f2bf(W1[(size_t)(kc * 8 + 2 * j + 1) * 3072 + r]);
            po[j] = (unsigned int)lo | ((unsigned int)hi << 16);
        }
        size_t dst = ((size_t)(r >> 6) * 12 + (kc >> 3)) * 4096
                   + (size_t)((kc & 7) * 64 + (r & 63)) * 8;
        *(uint4*)(W1t + dst) = make_uint4(po[0], po[1], po[2], po[3]);
    } else if (idx < C1n + PKn) {
        int t = idx - C1n;
        int r  = t % 384;
        int kc = t / 384;
        uint4 o = make_uint4(0u, 0u, 0u, 0u);
        if (r < 324) {
            const float* src = (r < 128) ? (S + (size_t)r * 768 + kc * 8)
                                         : (P + (size_t)(r - 128) * 768 + kc * 8);
            float4 a = *(const float4*)(src);
            float4 b = *(const float4*)(src + 4);
            o.x = (unsigned int)f2bf(a.x) | ((unsigned int)f2bf(a.y) << 16);
            o.y = (unsigned int)f2bf(a.z) | ((unsigned int)f2bf(a.w) << 16);
            o.z = (unsigned int)f2bf(b.x) | ((unsigned int)f2bf(b.y) << 16);
            o.w = (unsigned int)f2bf(b.z) | ((unsigned int)f2bf(b.w) << 16);
        }
        size_t dst = ((size_t)(r >> 6) * 12 + (kc >> 3)) * 4096
                   + (size_t)((kc & 7) * 64 + (r & 63)) * 8;
        *(uint4*)(A1 + dst) = o;
    }
}

// ---- GEMM1 (288 tiles, BM=BN=64, 3-stage, XCD nt-swizzle) + W2t (1152 blocks) ----
__launch_bounds__(256)
__global__ void k_gemm1_w2t(const unsigned short* __restrict__ A,
                            const unsigned short* __restrict__ Bt,
                            float* __restrict__ C,
                            const float* __restrict__ W2,
                            unsigned short* __restrict__ W2t) {
    const int tid = threadIdx.x;
    if (blockIdx.x >= 288) {            // ---- W2t conversion ----
        int idx = (blockIdx.x - 288) * 256 + tid;    // 0..294911
        int r  = idx % 768;
        int kc = idx / 768;             // 0..383
        unsigned int po[4];
        #pragma unroll
        for (int j = 0; j < 4; ++j) {
            unsigned short lo = f2bf(W2[(size_t)(kc * 8 + 2 * j) * 768 + r]);
            unsigned short hi = f2bf(W2[(size_t)(kc * 8 + 2 * j + 1) * 768 + r]);
            po[j] = (unsigned int)lo | ((unsigned int)hi << 16);
        }
        size_t dst = ((size_t)(r >> 6) * 48 + (kc >> 3)) * 4096
                   + (size_t)((kc & 7) * 64 + (r & 63)) * 8;
        *(uint4*)(W2t + dst) = make_uint4(po[0], po[1], po[2], po[3]);
        return;
    }

    __shared__ unsigned short sm[3 * 8192];   // 48 KB
    const int lane = tid & 63;
    const int wave = tid >> 6;
    const int wm = wave >> 1, wn = wave & 1;
    const int q = lane >> 4, l16 = lane & 15;

    // swizzle: XCD x = id&7 owns nt in [6x, 6x+6) -> W1t slice L2-resident
    const int id = blockIdx.x;
    const int j  = id >> 3;
    const int nt = (id & 7) * 6 + j % 6;
    const int rt = j / 6;

    const unsigned short* Ab = A  + (size_t)rt * 12 * 4096;
    const unsigned short* Bb = Bt + (size_t)nt * 12 * 4096;

    f32x4 acc[2][2] = {};
    const int offA = (wm * 32 + l16) * 8;
    const int offB = 4096 + (wn * 32 + l16) * 8;

    auto stage = [&](int i, unsigned short* d) {     // 4 loads/thread
        const unsigned short* Ag = Ab + (size_t)i * 4096;
        const unsigned short* Bg = Bb + (size_t)i * 4096;
        gld_lds16(Ag + tid * 8,        d + tid * 8);
        gld_lds16(Ag + 2048 + tid * 8, d + 2048 + tid * 8);
        gld_lds16(Bg + tid * 8,        d + 4096 + tid * 8);
        gld_lds16(Bg + 2048 + tid * 8, d + 6144 + tid * 8);
    };
    auto compute = [&](const unsigned short* buf) {
        #pragma unroll
        for (int ks = 0; ks < 2; ++ks) {
            const int ko = (ks * 4 + q) * 512;
            bf16x8 af0 = *(const bf16x8*)(buf + ko + offA);
            bf16x8 af1 = *(const bf16x8*)(buf + ko + offA + 128);
            bf16x8 bf0 = *(const bf16x8*)(buf + ko + offB);
            bf16x8 bf1 = *(const bf16x8*)(buf + ko + offB + 128);
            acc[0][0] = __builtin_amdgcn_mfma_f32_16x16x32_bf16(af0, bf0, acc[0][0], 0, 0, 0);
            acc[0][1] = __builtin_amdgcn_mfma_f32_16x16x32_bf16(af0, bf1, acc[0][1], 0, 0, 0);
            acc[1][0] = __builtin_amdgcn_mfma_f32_16x16x32_bf16(af1, bf0, acc[1][0], 0, 0, 0);
            acc[1][1] = __builtin_amdgcn_mfma_f32_16x16x32_bf16(af1, bf1, acc[1][1], 0, 0, 0);
        }
    };

    unsigned short* s0 = sm;
    unsigned short* s1 = sm + 8192;
    unsigned short* s2 = sm + 16384;

    stage(0, s0);
    stage(1, s1);
    for (int i = 0; i < 12; i += 3) {
        stage(i + 2, s2); WAIT_VM(8);
        BAR(); compute(s0); BAR_LDS();
        if (i + 3 < 12) { stage(i + 3, s0); WAIT_VM(8); } else { WAIT_VM(4); }
        BAR(); compute(s1); BAR_LDS();
        if (i + 4 < 12) { stage(i + 4, s1); WAIT_VM(8); }
        else if (i + 3 < 12) { WAIT_VM(4); }
        else { WAIT_VM(0); }
        BAR(); compute(s2);
        if (i + 3 < 12) BAR_LDS();
    }

    const int row0 = rt * 64 + wm * 32;
    const int col0 = nt * 64 + wn * 32;
    #pragma unroll
    for (int ii = 0; ii < 2; ++ii) {
        #pragma unroll
        for (int jj = 0; jj < 2; ++jj) {
            int col = col0 + jj * 16 + l16;
            #pragma unroll
            for (int r = 0; r < 4; ++r) {
                int row = row0 + ii * 16 + q * 4 + r;
                if (row < 324) C[(size_t)row * 3072 + col] = acc[ii][jj][r];
            }
        }
    }
}

// ---- hbar: Hb atoms (50 row-atoms w/ clamp), 4800 blocks ----
__global__ void k_hbar(const float* __restrict__ C1, const float* __restrict__ b1,
                       unsigned short* __restrict__ Hb) {
    const int bid  = blockIdx.x;
    const int tid  = threadIdx.x;
    const int bx   = bid % 50;                     // row-atom 0..49
    const int yq   = bid / 50;                     // 0..95
    const int lane = tid & 63;
    const int wv   = tid >> 6;
    const int hc   = yq * 4 + wv;                  // 0..383
    const int h0   = hc * 8;
    int bn = bx * 64 + lane;
    if (bn > 3135) bn = 3135;                      // clamp (dup rows never stored)
    const int b = bn / 196;
    const int n = bn - b * 196;
    const float* prow = C1 + (size_t)(128 + n) * 3072 + h0;
    float4 pA = *(const float4*)(prow);
    float4 pB = *(const float4*)(prow + 4);
    float4 bA = *(const float4*)(b1 + h0);
    float4 bB = *(const float4*)(b1 + h0 + 4);
    float pb[8] = { pA.x + bA.x, pA.y + bA.y, pA.z + bA.z, pA.w + bA.w,
                    pB.x + bB.x, pB.y + bB.y, pB.z + bB.z, pB.w + bB.w };
    float acc[8] = {};
    #pragma unroll
    for (int k = 0; k < 8; ++k) {
        const float* srow = C1 + (size_t)(b * 8 + k) * 3072 + h0;  // wave-broadcast-ish
        float4 sA_ = *(const float4*)(srow);
        float4 sB_ = *(const float4*)(srow + 4);
        acc[0] += fmaxf(sA_.x + pb[0], 0.f);
        acc[1] += fmaxf(sA_.y + pb[1], 0.f);
        acc[2] += fmaxf(sA_.z + pb[2], 0.f);
        acc[3] += fmaxf(sA_.w + pb[3], 0.f);
        acc[4] += fmaxf(sB_.x + pb[4], 0.f);
        acc[5] += fmaxf(sB_.y + pb[5], 0.f);
        acc[6] += fmaxf(sB_.z + pb[6], 0.f);
        acc[7] += fmaxf(sB_.w + pb[7], 0.f);
    }
    unsigned int w0 = (unsigned int)f2bf(acc[0] * 0.125f) | ((unsigned int)f2bf(acc[1] * 0.125f) << 16);
    unsigned int w1 = (unsigned int)f2bf(acc[2] * 0.125f) | ((unsigned int)f2bf(acc[3] * 0.125f) << 16);
    unsigned int w2 = (unsigned int)f2bf(acc[4] * 0.125f) | ((unsigned int)f2bf(acc[5] * 0.125f) << 16);
    unsigned int w3 = (unsigned int)f2bf(acc[6] * 0.125f) | ((unsigned int)f2bf(acc[7] * 0.125f) << 16);
    size_t dst = ((size_t)bx * 48 + (hc >> 3)) * 4096
               + (size_t)((hc & 7) * 64 + lane) * 8;
    *(uint4*)(Hb + dst) = make_uint4(w0, w1, w2, w3);
}

// ---- GEMM2: BM=128, BN=64, 128 threads = 2 waves, wave-tile 64x64 ----
// Min LDS-read redundancy (A x1, B x2): 32 KB reads per 24 KB staged per iter.
// Hb atoms [50][48][4096]; W2t atoms [12][48][4096]; out 3136x768 f32 + b2.
// rt-partition XCD swizzle as before; 3-stage global_load_lds pipeline.
__launch_bounds__(128)
__global__ void k_gemm2(const unsigned short* __restrict__ Hb,
                        const unsigned short* __restrict__ W2t,
                        const float* __restrict__ b2, float* __restrict__ out) {
    __shared__ unsigned short sm[3 * 12288];   // 72 KB: [stage][A0|A1|B]

    const int tid  = threadIdx.x;              // 0..127
    const int lane = tid & 63;
    const int w    = tid >> 6;                 // 0..1: wave -> 64-row half
    const int q = lane >> 4, l16 = lane & 15;

    // rt-partition swizzle: XCD x = id&7 handles rt in {x, x+8, x+16} (+ tail rt 24)
    const int id = blockIdx.x;
    int rt, nt;
    if (id < 288) { rt = (id / 96) * 8 + (id & 7); nt = (id % 96) >> 3; }
    else          { rt = 24; nt = id - 288; }

    const unsigned short* A0b = Hb  + ((size_t)(2 * rt)     * 48) * 4096;
    const unsigned short* A1b = Hb  + ((size_t)(2 * rt + 1) * 48) * 4096;
    const unsigned short* Bb  = W2t + ((size_t)nt * 48) * 4096;

    f32x4 acc[4][4] = {};

    auto stage = [&](int i, unsigned short* d) {   // 12 loads/thread (128 thr)
        const unsigned short* Ag0 = A0b + (size_t)i * 4096;
        const unsigned short* Ag1 = A1b + (size_t)i * 4096;
        const unsigned short* Bg  = Bb  + (size_t)i * 4096;
        #pragma unroll
        for (int u = 0; u < 4; ++u) {
            const int c = (u * 128 + tid) * 8;
            gld_lds16(Ag0 + c, d + c);
            gld_lds16(Ag1 + c, d + 4096 + c);
            gld_lds16(Bg  + c, d + 8192 + c);
        }
    };

    const int abase = w * 4096;                    // my wave's A atom
    auto compute = [&](const unsigned short* buf) {
        #pragma unroll
        for (int ks = 0; ks < 2; ++ks) {
            const int ko = (ks * 4 + q) * 512;     // chunk kb=(ks*4+q), 512 elems/chunk-row
            bf16x8 af[4], bfr[4];
            #pragma unroll
            for (int ii = 0; ii < 4; ++ii)
                af[ii] = *(const bf16x8*)(buf + abase + ko + (ii * 16 + l16) * 8);
            #pragma unroll
            for (int jj = 0; jj < 4; ++jj)
                bfr[jj] = *(const bf16x8*)(buf + 8192 + ko + (jj * 16 + l16) * 8);
            #pragma unroll
            for (int ii = 0; ii < 4; ++ii)
                #pragma unroll
                for (int jj = 0; jj < 4; ++jj)
                    acc[ii][jj] = __builtin_amdgcn_mfma_f32_16x16x32_bf16(
                        af[ii], bfr[jj], acc[ii][jj], 0, 0, 0);
        }
    };

    unsigned short* s0 = sm;
    unsigned short* s1 = sm + 12288;
    unsigned short* s2 = sm + 24576;

    stage(0, s0);
    stage(1, s1);
    for (int i = 0; i < 48; i += 3) {
        stage(i + 2, s2); WAIT_VM(24);
        BAR(); compute(s0); BAR_LDS();
        if (i + 3 < 48) { stage(i + 3, s0); WAIT_VM(24); } else { WAIT_VM(12); }
        BAR(); compute(s1); BAR_LDS();
        if (i + 4 < 48) { stage(i + 4, s1); WAIT_VM(24); }
        else if (i + 3 < 48) { WAIT_VM(12); }
        else { WAIT_VM(0); }
        BAR(); compute(s2);
        if (i + 3 < 48) BAR_LDS();
    }

    // epilogue: C/D col=lane&15, row=(lane>>4)*4+reg
    const int row0 = rt * 128 + w * 64;
    const int col0 = nt * 64;
    #pragma unroll
    for (int ii = 0; ii < 4; ++ii) {
        #pragma unroll
        for (int jj = 0; jj < 4; ++jj) {
            int col = col0 + jj * 16 + l16;
            float bv = b2[col];
            #pragma unroll
            for (int r = 0; r < 4; ++r) {
                int row = row0 + ii * 16 + q * 4 + r;
                if (row < 3136) out[(size_t)row * 768 + col] = acc[ii][jj][r] + bv;
            }
        }
    }
}

extern "C" void kernel_launch(void* const* d_in, const int* in_sizes, int n_in,
                              void* d_out, int out_size, void* d_ws, size_t ws_size,
                              hipStream_t stream) {
    const float* slots  = (const float*)d_in[0];   // 16*8*768
    const float* pos    = (const float*)d_in[1];   // 196*768
    // d_in[2] = map_alpha: unused (softmax over K of identical values = 1/K)
    const float* W1     = (const float*)d_in[3];   // 768*3072
    const float* b1     = (const float*)d_in[4];   // 3072
    const float* W2     = (const float*)d_in[5];   // 3072*768
    const float* b2     = (const float*)d_in[6];   // 768
    float* out = (float*)d_out;                    // 3136*768 f32

    size_t off = 0;
    auto alloc = [&](size_t bytes) {
        void* p = (char*)d_ws + off;
        off += (bytes + 255) & ~(size_t)255;
        return p;
    };
    unsigned short* W1t = (unsigned short*)alloc((size_t)3072 * 768 * 2);     // [48][12] atoms
    unsigned short* W2t = (unsigned short*)alloc((size_t)768 * 3072 * 2);     // [12][48] atoms
    unsigned short* A1  = (unsigned short*)alloc((size_t)384 * 768 * 2);      // [6][12] atoms
    float*          C1  = (float*)alloc((size_t)384 * 3072 * 4);              // row-major
    unsigned short* Hb  = (unsigned short*)alloc((size_t)50 * 48 * 4096 * 2); // [50][48] atoms

    // 1) prep: W1t + A1 (331776 tasks, 1296 blocks)
    k_prep<<<1296, 256, 0, stream>>>(W1, W1t, slots, pos, A1);
    // 2) GEMM1 (288 swizzled tiles) + W2t conversion (1152 blocks)
    k_gemm1_w2t<<<1440, 256, 0, stream>>>(A1, W1t, C1, W2, W2t);
    // 3) hbar -> Hb atoms (4800 blocks)
    k_hbar<<<4800, 256, 0, stream>>>(C1, b1, Hb);
    // 4) out = Hb @ W2t^T + b2 (300 blocks x 128 thr, wave-tile 64x64)
    k_gemm2<<<300, 128, 0, stream>>>(Hb, W2t, b2, out);
}

// Round 12
// 127.933 us; speedup vs baseline: 1.1471x; 1.1471x over previous
//
#include <hip/hip_runtime.h>
#include <hip/hip_bf16.h>
#include <stdint.h>

// B=16, K=8, N=196, D=768, H=3072, DOUT=768
// y[b,n,:] = (mean_k relu(slots[b,k]@W1 + pos[n]@W1 + b1)) @ W2 + b2
// (softmax over K of K-identical values is exactly 1/K; map_alpha unused)
//
// Dispatches:
//  k_prep:      W1->W1t atoms + A1=[slots;pos] atoms (bf16)
//  k_gemm1_w2t: C1 = A1 @ W1t^T (288 tiles, XCD nt-swizzle) + W2->W2t (1152 blks)
//  k_hbar:      Hb atoms (49 row-atoms, 4704 blocks)
//  k_gemm2:     out = Hb @ W2t^T + b2. BM=BN=64, 512 thr (8 waves 4x2,
//               wave-tile 16x32 — TLP-maximizing per R11 lesson), 3-stage,
//               588 blocks, rt-XCD partition swizzle.
// Atom = 64x64 bf16 tile, image [kb 0..7][r 0..63] chunks of 8; off=(kb*64+r)*8.

typedef __attribute__((ext_vector_type(8))) short bf16x8;
typedef __attribute__((ext_vector_type(4))) float f32x4;

#define AS1 __attribute__((address_space(1)))
#define AS3 __attribute__((address_space(3)))

#define WAIT_VM(N) asm volatile("s_waitcnt vmcnt(" #N ")" ::: "memory")
#define BAR()      asm volatile("s_barrier" ::: "memory")
#define BAR_LDS()  asm volatile("s_waitcnt lgkmcnt(0)\ns_barrier" ::: "memory")

static __device__ __forceinline__ void gld_lds16(const void* g, void* l) {
    __builtin_amdgcn_global_load_lds((const AS1 unsigned int*)g,
                                     (AS3 unsigned int*)l, 16, 0, 0);
}

static __device__ __forceinline__ unsigned short f2bf(float f) {
    union { float f; unsigned int u; } v; v.f = f;
    unsigned int u = v.u;
    return (unsigned short)((u + 0x7fffu + ((u >> 16) & 1u)) >> 16);  // RNE
}

// ---------------- prep: W1t tiled transpose + A1 tiled pack ----------------
__global__ void k_prep(const float* __restrict__ W1, unsigned short* __restrict__ W1t,
                       const float* __restrict__ S, const float* __restrict__ P,
                       unsigned short* __restrict__ A1) {
    int idx = blockIdx.x * blockDim.x + threadIdx.x;
    const int C1n = 96 * 3072;          // W1t tasks
    const int PKn = 96 * 384;           // A1 tasks
    if (idx < C1n) {
        int r  = idx % 3072;            // consecutive tid -> consecutive r (coalesced)
        int kc = idx / 3072;            // 8-elem k-chunk (0..95)
        unsigned int po[4];
        #pragma unroll
        for (int j = 0; j < 4; ++j) {
            unsigned short lo = f2bf(W1[(size_t)(kc * 8 + 2 * j) * 3072 + r]);
            unsigned short hi = f2bf(W1[(size_t)(kc * 8 + 2 * j + 1) * 3072 + r]);
            po[j] = (unsigned int)lo | ((unsigned int)hi << 16);
        }
        size_t dst = ((size_t)(r >> 6) * 12 + (kc >> 3)) * 4096
                   + (size_t)((kc & 7) * 64 + (r & 63)) * 8;
        *(uint4*)(W1t + dst) = make_uint4(po[0], po[1], po[2], po[3]);
    } else if (idx < C1n + PKn) {
        int t = idx - C1n;
        int r  = t % 384;
        int kc = t / 384;
        uint4 o = make_uint4(0u, 0u, 0u, 0u);
        if (r < 324) {
            const float* src = (r < 128) ? (S + (size_t)r * 768 + kc * 8)
                                         : (P + (size_t)(r - 128) * 768 + kc * 8);
            float4 a = *(const float4*)(src);
            float4 b = *(const float4*)(src + 4);
            o.x = (unsigned int)f2bf(a.x) | ((unsigned int)f2bf(a.y) << 16);
            o.y = (unsigned int)f2bf(a.z) | ((unsigned int)f2bf(a.w) << 16);
            o.z = (unsigned int)f2bf(b.x) | ((unsigned int)f2bf(b.y) << 16);
            o.w = (unsigned int)f2bf(b.z) | ((unsigned int)f2bf(b.w) << 16);
        }
        size_t dst = ((size_t)(r >> 6) * 12 + (kc >> 3)) * 4096
                   + (size_t)((kc & 7) * 64 + (r & 63)) * 8;
        *(uint4*)(A1 + dst) = o;
    }
}

// ---- GEMM1 (288 tiles, BM=BN=64, 3-stage, XCD nt-swizzle) + W2t (1152 blocks) ----
__launch_bounds__(256)
__global__ void k_gemm1_w2t(const unsigned short* __restrict__ A,
                            const unsigned short* __restrict__ Bt,
                            float* __restrict__ C,
                            const float* __restrict__ W2,
                            unsigned short* __restrict__ W2t) {
    const int tid = threadIdx.x;
    if (blockIdx.x >= 288) {            // ---- W2t conversion ----
        int idx = (blockIdx.x - 288) * 256 + tid;    // 0..294911
        int r  = idx % 768;
        int kc = idx / 768;             // 0..383
        unsigned int po[4];
        #pragma unroll
        for (int j = 0; j < 4; ++j) {
            unsigned short lo = f2bf(W2[(size_t)(kc * 8 + 2 * j) * 768 + r]);
            unsigned short hi = f2bf(W2[(size_t)(kc * 8 + 2 * j + 1) * 768 + r]);
            po[j] = (unsigned int)lo | ((unsigned int)hi << 16);
        }
        size_t dst = ((size_t)(r >> 6) * 48 + (kc >> 3)) * 4096
                   + (size_t)((kc & 7) * 64 + (r & 63)) * 8;
        *(uint4*)(W2t + dst) = make_uint4(po[0], po[1], po[2], po[3]);
        return;
    }

    __shared__ unsigned short sm[3 * 8192];   // 48 KB
    const int lane = tid & 63;
    const int wave = tid >> 6;
    const int wm = wave >> 1, wn = wave & 1;
    const int q = lane >> 4, l16 = lane & 15;

    // swizzle: XCD x = id&7 owns nt in [6x, 6x+6) -> W1t slice L2-resident
    const int id = blockIdx.x;
    const int j  = id >> 3;
    const int nt = (id & 7) * 6 + j % 6;
    const int rt = j / 6;

    const unsigned short* Ab = A  + (size_t)rt * 12 * 4096;
    const unsigned short* Bb = Bt + (size_t)nt * 12 * 4096;

    f32x4 acc[2][2] = {};
    const int offA = (wm * 32 + l16) * 8;
    const int offB = 4096 + (wn * 32 + l16) * 8;

    auto stage = [&](int i, unsigned short* d) {     // 4 loads/thread
        const unsigned short* Ag = Ab + (size_t)i * 4096;
        const unsigned short* Bg = Bb + (size_t)i * 4096;
        gld_lds16(Ag + tid * 8,        d + tid * 8);
        gld_lds16(Ag + 2048 + tid * 8, d + 2048 + tid * 8);
        gld_lds16(Bg + tid * 8,        d + 4096 + tid * 8);
        gld_lds16(Bg + 2048 + tid * 8, d + 6144 + tid * 8);
    };
    auto compute = [&](const unsigned short* buf) {
        #pragma unroll
        for (int ks = 0; ks < 2; ++ks) {
            const int ko = (ks * 4 + q) * 512;
            bf16x8 af0 = *(const bf16x8*)(buf + ko + offA);
            bf16x8 af1 = *(const bf16x8*)(buf + ko + offA + 128);
            bf16x8 bf0 = *(const bf16x8*)(buf + ko + offB);
            bf16x8 bf1 = *(const bf16x8*)(buf + ko + offB + 128);
            acc[0][0] = __builtin_amdgcn_mfma_f32_16x16x32_bf16(af0, bf0, acc[0][0], 0, 0, 0);
            acc[0][1] = __builtin_amdgcn_mfma_f32_16x16x32_bf16(af0, bf1, acc[0][1], 0, 0, 0);
            acc[1][0] = __builtin_amdgcn_mfma_f32_16x16x32_bf16(af1, bf0, acc[1][0], 0, 0, 0);
            acc[1][1] = __builtin_amdgcn_mfma_f32_16x16x32_bf16(af1, bf1, acc[1][1], 0, 0, 0);
        }
    };

    unsigned short* s0 = sm;
    unsigned short* s1 = sm + 8192;
    unsigned short* s2 = sm + 16384;

    stage(0, s0);
    stage(1, s1);
    for (int i = 0; i < 12; i += 3) {
        stage(i + 2, s2); WAIT_VM(8);
        BAR(); compute(s0); BAR_LDS();
        if (i + 3 < 12) { stage(i + 3, s0); WAIT_VM(8); } else { WAIT_VM(4); }
        BAR(); compute(s1); BAR_LDS();
        if (i + 4 < 12) { stage(i + 4, s1); WAIT_VM(8); }
        else if (i + 3 < 12) { WAIT_VM(4); }
        else { WAIT_VM(0); }
        BAR(); compute(s2);
        if (i + 3 < 12) BAR_LDS();
    }

    const int row0 = rt * 64 + wm * 32;
    const int col0 = nt * 64 + wn * 32;
    #pragma unroll
    for (int ii = 0; ii < 2; ++ii) {
        #pragma unroll
        for (int jj = 0; jj < 2; ++jj) {
            int col = col0 + jj * 16 + l16;
            #pragma unroll
            for (int r = 0; r < 4; ++r) {
                int row = row0 + ii * 16 + q * 4 + r;
                if (row < 324) C[(size_t)row * 3072 + col] = acc[ii][jj][r];
            }
        }
    }
}

// ---- hbar: Hb atoms (49 row-atoms), 4704 blocks ----
__global__ void k_hbar(const float* __restrict__ C1, const float* __restrict__ b1,
                       unsigned short* __restrict__ Hb) {
    const int bid  = blockIdx.x;
    const int tid  = threadIdx.x;
    const int bx   = bid % 49;                     // row-atom 0..48
    const int yq   = bid / 49;                     // 0..95
    const int lane = tid & 63;
    const int wv   = tid >> 6;
    const int hc   = yq * 4 + wv;                  // 0..383
    const int h0   = hc * 8;
    const int bn   = bx * 64 + lane;               // 0..3135 (49*64=3136 exact)
    const int b    = bn / 196;
    const int n    = bn - b * 196;
    const float* prow = C1 + (size_t)(128 + n) * 3072 + h0;
    float4 pA = *(const float4*)(prow);
    float4 pB = *(const float4*)(prow + 4);
    float4 bA = *(const float4*)(b1 + h0);
    float4 bB = *(const float4*)(b1 + h0 + 4);
    float pb[8] = { pA.x + bA.x, pA.y + bA.y, pA.z + bA.z, pA.w + bA.w,
                    pB.x + bB.x, pB.y + bB.y, pB.z + bB.z, pB.w + bB.w };
    float acc[8] = {};
    #pragma unroll
    for (int k = 0; k < 8; ++k) {
        const float* srow = C1 + (size_t)(b * 8 + k) * 3072 + h0;  // wave-broadcast-ish
        float4 sA_ = *(const float4*)(srow);
        float4 sB_ = *(const float4*)(srow + 4);
        acc[0] += fmaxf(sA_.x + pb[0], 0.f);
        acc[1] += fmaxf(sA_.y + pb[1], 0.f);
        acc[2] += fmaxf(sA_.z + pb[2], 0.f);
        acc[3] += fmaxf(sA_.w + pb[3], 0.f);
        acc[4] += fmaxf(sB_.x + pb[4], 0.f);
        acc[5] += fmaxf(sB_.y + pb[5], 0.f);
        acc[6] += fmaxf(sB_.z + pb[6], 0.f);
        acc[7] += fmaxf(sB_.w + pb[7], 0.f);
    }
    unsigned int w0 = (unsigned int)f2bf(acc[0] * 0.125f) | ((unsigned int)f2bf(acc[1] * 0.125f) << 16);
    unsigned int w1 = (unsigned int)f2bf(acc[2] * 0.125f) | ((unsigned int)f2bf(acc[3] * 0.125f) << 16);
    unsigned int w2 = (unsigned int)f2bf(acc[4] * 0.125f) | ((unsigned int)f2bf(acc[5] * 0.125f) << 16);
    unsigned int w3 = (unsigned int)f2bf(acc[6] * 0.125f) | ((unsigned int)f2bf(acc[7] * 0.125f) << 16);
    size_t dst = ((size_t)bx * 48 + (hc >> 3)) * 4096
               + (size_t)((hc & 7) * 64 + lane) * 8;
    *(uint4*)(Hb + dst) = make_uint4(w0, w1, w2, w3);
}

// ---- GEMM2: BM=BN=64, 512 threads (8 waves 4x2, wave-tile 16x32), 3-stage ----
// 588 blocks (49 rt x 12 nt), rt-XCD partition: rt=(id&7)+8*((id>>3)%6), tail rt=48.
// Hb atoms [49][48][4096]; W2t atoms [12][48][4096]; out 3136x768 f32 + b2.
// TLP-maximizing config (R11 lesson: wave count >> LDS-read redundancy).
__launch_bounds__(512)
__global__ void k_gemm2(const unsigned short* __restrict__ Hb,
                        const unsigned short* __restrict__ W2t,
                        const float* __restrict__ b2, float* __restrict__ out) {
    __shared__ unsigned short sm[3 * 8192];    // 48 KB: [stage][A 4096 | B 4096 elems]

    const int tid  = threadIdx.x;              // 0..511
    const int lane = tid & 63;
    const int wave = tid >> 6;                 // 0..7
    const int wm = wave >> 1, wn = wave & 1;   // 4 x 2 wave grid, tile 16x32
    const int q = lane >> 4, l16 = lane & 15;

    const int id = blockIdx.x;
    int rt, nt;
    if (id < 576) { rt = (id & 7) + 8 * ((id >> 3) % 6); nt = (id >> 3) / 6; }
    else          { rt = 48; nt = id - 576; }

    const unsigned short* Ab = Hb  + (size_t)rt * 48 * 4096;
    const unsigned short* Bb = W2t + (size_t)nt * 48 * 4096;

    f32x4 acc[2] = {};

    auto stage = [&](int i, unsigned short* d) {   // 2 loads/thread (512 thr x 16B = 8KB each)
        gld_lds16(Ab + (size_t)i * 4096 + tid * 8, d + tid * 8);
        gld_lds16(Bb + (size_t)i * 4096 + tid * 8, d + 4096 + tid * 8);
    };

    const int offA = (wm * 16 + l16) * 8;
    const int offB = 4096 + (wn * 32 + l16) * 8;
    auto compute = [&](const unsigned short* buf) {
        #pragma unroll
        for (int ks = 0; ks < 2; ++ks) {
            const int ko = (ks * 4 + q) * 512;
            bf16x8 af  = *(const bf16x8*)(buf + ko + offA);
            bf16x8 bf0 = *(const bf16x8*)(buf + ko + offB);
            bf16x8 bf1 = *(const bf16x8*)(buf + ko + offB + 128);
            acc[0] = __builtin_amdgcn_mfma_f32_16x16x32_bf16(af, bf0, acc[0], 0, 0, 0);
            acc[1] = __builtin_amdgcn_mfma_f32_16x16x32_bf16(af, bf1, acc[1], 0, 0, 0);
        }
    };

    unsigned short* s0 = sm;
    unsigned short* s1 = sm + 8192;
    unsigned short* s2 = sm + 16384;

    stage(0, s0);
    stage(1, s1);
    for (int i = 0; i < 48; i += 3) {
        stage(i + 2, s2); WAIT_VM(4);
        BAR(); compute(s0); BAR_LDS();
        if (i + 3 < 48) { stage(i + 3, s0); WAIT_VM(4); } else { WAIT_VM(2); }
        BAR(); compute(s1); BAR_LDS();
        if (i + 4 < 48) { stage(i + 4, s1); WAIT_VM(4); }
        else if (i + 3 < 48) { WAIT_VM(2); }
        else { WAIT_VM(0); }
        BAR(); compute(s2);
        if (i + 3 < 48) BAR_LDS();
    }

    // epilogue: C/D col=lane&15, row=(lane>>4)*4+reg; 3136 = 49*64 -> no bounds
    const int row0 = rt * 64 + wm * 16;
    const int col0 = nt * 64 + wn * 32;
    #pragma unroll
    for (int jj = 0; jj < 2; ++jj) {
        int col = col0 + jj * 16 + l16;
        float bv = b2[col];
        #pragma unroll
        for (int r = 0; r < 4; ++r) {
            int row = row0 + q * 4 + r;
            out[(size_t)row * 768 + col] = acc[jj][r] + bv;
        }
    }
}

extern "C" void kernel_launch(void* const* d_in, const int* in_sizes, int n_in,
                              void* d_out, int out_size, void* d_ws, size_t ws_size,
                              hipStream_t stream) {
    const float* slots  = (const float*)d_in[0];   // 16*8*768
    const float* pos    = (const float*)d_in[1];   // 196*768
    // d_in[2] = map_alpha: unused (softmax over K of identical values = 1/K)
    const float* W1     = (const float*)d_in[3];   // 768*3072
    const float* b1     = (const float*)d_in[4];   // 3072
    const float* W2     = (const float*)d_in[5];   // 3072*768
    const float* b2     = (const float*)d_in[6];   // 768
    float* out = (float*)d_out;                    // 3136*768 f32

    size_t off = 0;
    auto alloc = [&](size_t bytes) {
        void* p = (char*)d_ws + off;
        off += (bytes + 255) & ~(size_t)255;
        return p;
    };
    unsigned short* W1t = (unsigned short*)alloc((size_t)3072 * 768 * 2);     // [48][12] atoms
    unsigned short* W2t = (unsigned short*)alloc((size_t)768 * 3072 * 2);     // [12][48] atoms
    unsigned short* A1  = (unsigned short*)alloc((size_t)384 * 768 * 2);      // [6][12] atoms
    float*          C1  = (float*)alloc((size_t)384 * 3072 * 4);              // row-major
    unsigned short* Hb  = (unsigned short*)alloc((size_t)49 * 48 * 4096 * 2); // [49][48] atoms

    // 1) prep: W1t + A1 (331776 tasks, 1296 blocks)
    k_prep<<<1296, 256, 0, stream>>>(W1, W1t, slots, pos, A1);
    // 2) GEMM1 (288 swizzled tiles) + W2t conversion (1152 blocks)
    k_gemm1_w2t<<<1440, 256, 0, stream>>>(A1, W1t, C1, W2, W2t);
    // 3) hbar -> Hb atoms (4704 blocks)
    k_hbar<<<4704, 256, 0, stream>>>(C1, b1, Hb);
    // 4) out = Hb @ W2t^T + b2 (588 blocks x 512 thr, wave-tile 16x32)
    k_gemm2<<<588, 512, 0, stream>>>(Hb, W2t, b2, out);
}